// Round 7
// baseline (1197.445 us; speedup 1.0000x reference)
//
#include <hip/hip_runtime.h>
#include <hip/hip_bf16.h>

typedef __attribute__((ext_vector_type(8))) short short8;
typedef __attribute__((ext_vector_type(4))) float f32x4;

#define AS1 __attribute__((address_space(1)))
#define AS3 __attribute__((address_space(3)))

static __device__ __forceinline__ short f2bf(float f) {
    __hip_bfloat16 h = __float2bfloat16(f);
    union { __hip_bfloat16 h; short s; } u;
    u.h = h;
    return u.s;
}

// ---------------- prepack kernels ----------------

__global__ __launch_bounds__(256) void prepack_w_kernel(const int* __restrict__ wq,
                                                        const float* __restrict__ scales,
                                                        short* __restrict__ Wb,
                                                        long total8) {
    long i = (long)blockIdx.x * 256 + threadIdx.x;
    if (i >= total8) return;
    const int4* p = (const int4*)wq + i * 2;
    int4 q0 = p[0], q1 = p[1];
    float s = scales[(i * 8) >> 5];
    short8 v;
    v[0] = f2bf((float)(q0.x - 128) * s);
    v[1] = f2bf((float)(q0.y - 128) * s);
    v[2] = f2bf((float)(q0.z - 128) * s);
    v[3] = f2bf((float)(q0.w - 128) * s);
    v[4] = f2bf((float)(q1.x - 128) * s);
    v[5] = f2bf((float)(q1.y - 128) * s);
    v[6] = f2bf((float)(q1.z - 128) * s);
    v[7] = f2bf((float)(q1.w - 128) * s);
    ((short8*)Wb)[i] = v;
}

__global__ __launch_bounds__(256) void prepack_x_kernel(const float* __restrict__ x,
                                                        short* __restrict__ Xb,
                                                        long total8) {
    long i = (long)blockIdx.x * 256 + threadIdx.x;
    if (i >= total8) return;
    const float4* p = (const float4*)x + i * 2;
    float4 f0 = p[0], f1 = p[1];
    short8 v;
    v[0] = f2bf(f0.x); v[1] = f2bf(f0.y); v[2] = f2bf(f0.z); v[3] = f2bf(f0.w);
    v[4] = f2bf(f1.x); v[5] = f2bf(f1.y); v[6] = f2bf(f1.z); v[7] = f2bf(f1.w);
    ((short8*)Xb)[i] = v;
}

// ---------------- 256x256 GEMM: A direct-from-global, B via LDS, 1 barrier/K-tile ----
// 512 thr = 8 waves (2M x 4N), per-wave C = 128x64, BK=64, mfma 16x16x32.
// A fragments load straight from global (L1-resident 32KB/K-tile slice; kk-halves
// share 128B lines). B double-buffered in LDS (32KB/parity), staged reg->ds_write
// with granule XOR swizzle. All waits compiler-managed except one fused
// {lgkmcnt(0); s_barrier} per K-tile (protects B slot reuse + write visibility).
__global__ __launch_bounds__(512, 2)
void gemm256_kernel(const float* __restrict__ bias,
                    const short* __restrict__ Xb, const short* __restrict__ Wb,
                    float* __restrict__ out, int M, int N, int K) {
    __shared__ alignas(16) short Bs[2][256 * 64];

    const int nM = M >> 8, nN = N >> 8;
    int bid = blockIdx.x;
    {
        int nwg = nM * nN;
        if ((nwg & 7) == 0) bid = (bid & 7) * (nwg >> 3) + (bid >> 3);  // XCD swizzle
    }
    int pm, pn;
    {
        const int G = 8;
        if ((nN % G) == 0) {
            int per = nM * G;
            int grp = bid / per, in = bid % per;
            pn = grp * G + (in % G);
            pm = in / G;
        } else { pn = bid % nN; pm = bid / nN; }
    }

    const int tid  = threadIdx.x;
    const int lane = tid & 63;
    const int wid  = tid >> 6;
    const int wm   = wid >> 2;     // 0..1
    const int wn   = wid & 3;      // 0..3
    const int q4   = lane >> 4;
    const int l15  = lane & 15;
    const int lx   = lane & 7;

    const long bm = (long)pm << 8, bn = (long)pn << 8;
    const long Kl = K;
    const int  NT = K >> 6;

    // B LDS fragment read base (shorts): rows = wn*64 + n*16 + l15, row stride 64
    const int rB  = (wn * 64 + l15) * 64;
    const int sg0 = (q4 ^ lx) * 8;          // kk=0 granule (swizzled)
    const int sg1 = ((4 + q4) ^ lx) * 8;    // kk=1

    // B staging: thread t covers rows {i*64 + (t>>3)}, granule t&7 (4 issues)
    const int sRow = tid >> 3;              // 0..63
    const int sgr  = tid & 7;
    const short* bSrc = Wb + (bn + sRow) * Kl + sgr * 8;
    const int wOff = sRow * 64 + ((sgr ^ (sRow & 7)) * 8);   // + i*4096 (+64 rows)

    // A direct-load base: row = bm + wm*128 + l15, k-granule q4
    const short* aA = Xb + (bm + wm * 128 + l15) * Kl + q4 * 8;

    f32x4 acc[8][4];
#pragma unroll
    for (int m = 0; m < 8; ++m)
#pragma unroll
        for (int n = 0; n < 4; ++n) acc[m][n] = (f32x4){0.f, 0.f, 0.f, 0.f};

    short8 bfr[4][2];     // B fragments for this K-tile
    short8 breg[4];       // B staging in-flight (next tile)
    short8 pa00, pa01, pa10, pa11;  // preloaded A quad (mq=0) for next tile

#define LDB8(P) { _Pragma("unroll") for (int n = 0; n < 4; ++n) {                    \
    bfr[n][0] = *(const short8*)&Bs[P][rB + n * 1024 + sg0];                         \
    bfr[n][1] = *(const short8*)&Bs[P][rB + n * 1024 + sg1]; } }

#define MFMA16(MQ, A00, A01, A10, A11) {                                             \
    _Pragma("unroll") for (int n = 0; n < 4; ++n)                                    \
        acc[2*(MQ)][n] = __builtin_amdgcn_mfma_f32_16x16x32_bf16(                    \
            A00, bfr[n][0], acc[2*(MQ)][n], 0, 0, 0);                                \
    _Pragma("unroll") for (int n = 0; n < 4; ++n)                                    \
        acc[2*(MQ)][n] = __builtin_amdgcn_mfma_f32_16x16x32_bf16(                    \
            A01, bfr[n][1], acc[2*(MQ)][n], 0, 0, 0);                                \
    _Pragma("unroll") for (int n = 0; n < 4; ++n)                                    \
        acc[2*(MQ)+1][n] = __builtin_amdgcn_mfma_f32_16x16x32_bf16(                  \
            A10, bfr[n][0], acc[2*(MQ)+1][n], 0, 0, 0);                              \
    _Pragma("unroll") for (int n = 0; n < 4; ++n)                                    \
        acc[2*(MQ)+1][n] = __builtin_amdgcn_mfma_f32_16x16x32_bf16(                  \
            A11, bfr[n][1], acc[2*(MQ)+1][n], 0, 0, 0); }

// TILE body: parity P (literal), k-offset KO (shorts). DO_NEXT: stage B(t+1) and
// preload A-quad0(t+1).
#define TILE(P, KO, DO_NEXT) {                                                       \
    if (DO_NEXT) { _Pragma("unroll") for (int i = 0; i < 4; ++i)                     \
        breg[i] = *(const short8*)(bSrc + (long)i * 64 * Kl + (KO) + 64); }          \
    LDB8(P);                                                                         \
    __builtin_amdgcn_s_setprio(1);                                                   \
    MFMA16(0, pa00, pa01, pa10, pa11);                                               \
    {                                                                                \
        short8 a00 = *(const short8*)(aA + 32 * Kl + (KO));                          \
        short8 a01 = *(const short8*)(aA + 32 * Kl + (KO) + 32);                     \
        short8 a10 = *(const short8*)(aA + 48 * Kl + (KO));                          \
        short8 a11 = *(const short8*)(aA + 48 * Kl + (KO) + 32);                     \
        MFMA16(1, a00, a01, a10, a11);                                               \
    }                                                                                \
    {                                                                                \
        short8 a00 = *(const short8*)(aA + 64 * Kl + (KO));                          \
        short8 a01 = *(const short8*)(aA + 64 * Kl + (KO) + 32);                     \
        short8 a10 = *(const short8*)(aA + 80 * Kl + (KO));                          \
        short8 a11 = *(const short8*)(aA + 80 * Kl + (KO) + 32);                     \
        MFMA16(2, a00, a01, a10, a11);                                               \
    }                                                                                \
    if (DO_NEXT) { _Pragma("unroll") for (int i = 0; i < 4; ++i)                     \
        *(short8*)&Bs[(P) ^ 1][wOff + i * 4096] = breg[i]; }                         \
    {                                                                                \
        short8 a00 = *(const short8*)(aA + 96 * Kl + (KO));                          \
        short8 a01 = *(const short8*)(aA + 96 * Kl + (KO) + 32);                     \
        short8 a10 = *(const short8*)(aA + 112 * Kl + (KO));                         \
        short8 a11 = *(const short8*)(aA + 112 * Kl + (KO) + 32);                    \
        if (DO_NEXT) {                                                               \
            pa00 = *(const short8*)(aA + (KO) + 64);                                 \
            pa01 = *(const short8*)(aA + (KO) + 96);                                 \
            pa10 = *(const short8*)(aA + 16 * Kl + (KO) + 64);                       \
            pa11 = *(const short8*)(aA + 16 * Kl + (KO) + 96);                       \
        }                                                                            \
        MFMA16(3, a00, a01, a10, a11);                                               \
    }                                                                                \
    __builtin_amdgcn_s_setprio(0);                                                   \
    if (DO_NEXT) { asm volatile("s_waitcnt lgkmcnt(0)\n\ts_barrier" ::: "memory"); } \
}

    // ---- prologue: stage B(0) into parity 0; preload A quad0(0) ----
    {
        short8 t0[4];
#pragma unroll
        for (int i = 0; i < 4; ++i)
            t0[i] = *(const short8*)(bSrc + (long)i * 64 * Kl);
#pragma unroll
        for (int i = 0; i < 4; ++i)
            *(short8*)&Bs[0][wOff + i * 4096] = t0[i];
        pa00 = *(const short8*)(aA);
        pa01 = *(const short8*)(aA + 32);
        pa10 = *(const short8*)(aA + 16 * Kl);
        pa11 = *(const short8*)(aA + 16 * Kl + 32);
        asm volatile("s_waitcnt lgkmcnt(0)\n\ts_barrier" ::: "memory");
    }

    // ---- main loop: 2 K-tiles/iteration, literal parity ----
    for (int t = 0; t < NT - 2; t += 2) {
        const long ko0 = (long)t * 64;
        TILE(0, ko0, true);
        TILE(1, ko0 + 64, true);
    }
    // ---- final pair ----
    {
        const long ko0 = (long)(NT - 2) * 64;
        TILE(0, ko0, true);   // stages B(NT-1) -> parity 1
        TILE(1, ko0 + 64, false);
    }

    // ---- epilogue: C/D layout col = lane&15, row = (lane>>4)*4 + reg ----
#pragma unroll
    for (int n = 0; n < 4; ++n) {
        long col = bn + wn * 64 + n * 16 + l15;
        float bv = bias[col];
#pragma unroll
        for (int m = 0; m < 8; ++m) {
            long row = bm + wm * 128 + m * 16 + q4 * 4;
#pragma unroll
            for (int r = 0; r < 4; ++r)
                out[(row + r) * (long)N + col] = acc[m][n][r] + bv;
        }
    }
#undef TILE
#undef LDB8
#undef MFMA16
}

// ---------------- fallback 128x128 GEMM (handles fused / odd shapes) ----------------

template <bool PRE_A, bool PRE_B>
__global__ __launch_bounds__(256, 2)
void gemm_kernel(const float* __restrict__ x, const int* __restrict__ wq,
                 const float* __restrict__ scales, const float* __restrict__ bias,
                 const short* __restrict__ Xb, const short* __restrict__ Wb,
                 float* __restrict__ out, int M, int N, int K) {
    constexpr int BM = 128, BN = 128, BK = 64;
    __shared__ alignas(16) short As[BM * BK];
    __shared__ alignas(16) short Bs[BN * BK];

    const int nM = M / BM, nN = N / BN;
    int bid = blockIdx.x;
    int pm, pn;
    const int G = 8;
    if ((nN % G) == 0) {
        int per = nM * G;
        int grp = bid / per;
        int in  = bid % per;
        pn = grp * G + (in % G);
        pm = in / G;
    } else {
        pn = bid % nN;
        pm = bid / nN;
    }

    const int tid  = threadIdx.x;
    const int lane = tid & 63;
    const int wv   = tid >> 6;
    const int wm   = (wv >> 1) * 64;
    const int wn   = (wv & 1) * 64;
    const int q    = lane >> 4;
    const int l15  = lane & 15;
    const int sxor = lane & 7;

    const long bm = (long)pm * BM, bn = (long)pn * BN;

    f32x4 acc[4][4];
#pragma unroll
    for (int i = 0; i < 4; ++i)
#pragma unroll
        for (int j = 0; j < 4; ++j) acc[i][j] = (f32x4){0.f, 0.f, 0.f, 0.f};

    const int srow = tid >> 3;
    const int scg  = tid & 7;

    const int sg0   = q ^ sxor;
    const int aOff0 = (wm + l15) * 64 + sg0 * 8;
    const int aOff1 = (wm + l15) * 64 + (sg0 ^ 4) * 8;
    const int bOff0 = (wn + l15) * 64 + sg0 * 8;
    const int bOff1 = (wn + l15) * 64 + (sg0 ^ 4) * 8;

    const int prRow  = lane >> 3;
    const int prGsrc = (lane & 7) ^ (lane >> 3);

    for (int k0 = 0; k0 < K; k0 += BK) {
        if constexpr (PRE_A) {
#pragma unroll
            for (int i = 0; i < 4; ++i) {
                int r = wv * 32 + i * 8 + prRow;
                const short* src = Xb + (bm + r) * (long)K + k0 + prGsrc * 8;
                __builtin_amdgcn_global_load_lds((const AS1 void*)src,
                                                 (AS3 void*)&As[(wv * 32 + i * 8) * 64],
                                                 16, 0, 0);
            }
        } else {
#pragma unroll
            for (int i = 0; i < 4; ++i) {
                int r = i * 32 + srow;
                const float4* p = (const float4*)(x + (bm + r) * (long)K + k0 + scg * 8);
                float4 f0 = p[0], f1 = p[1];
                short8 v;
                v[0] = f2bf(f0.x); v[1] = f2bf(f0.y); v[2] = f2bf(f0.z); v[3] = f2bf(f0.w);
                v[4] = f2bf(f1.x); v[5] = f2bf(f1.y); v[6] = f2bf(f1.z); v[7] = f2bf(f1.w);
                int sg = scg ^ (r & 7);
                *(short8*)&As[r * 64 + sg * 8] = v;
            }
        }
        if constexpr (PRE_B) {
#pragma unroll
            for (int i = 0; i < 4; ++i) {
                int r = wv * 32 + i * 8 + prRow;
                const short* src = Wb + (bn + r) * (long)K + k0 + prGsrc * 8;
                __builtin_amdgcn_global_load_lds((const AS1 void*)src,
                                                 (AS3 void*)&Bs[(wv * 32 + i * 8) * 64],
                                                 16, 0, 0);
            }
        } else {
#pragma unroll
            for (int i = 0; i < 4; ++i) {
                int r = i * 32 + srow;
                const int4* p = (const int4*)(wq + (bn + r) * (long)K + k0 + scg * 8);
                int4 q0 = p[0], q1 = p[1];
                float s = scales[(bn + r) * (long)(K >> 5) + ((k0 + scg * 8) >> 5)];
                short8 v;
                v[0] = f2bf((float)(q0.x - 128) * s);
                v[1] = f2bf((float)(q0.y - 128) * s);
                v[2] = f2bf((float)(q0.z - 128) * s);
                v[3] = f2bf((float)(q0.w - 128) * s);
                v[4] = f2bf((float)(q1.x - 128) * s);
                v[5] = f2bf((float)(q1.y - 128) * s);
                v[6] = f2bf((float)(q1.z - 128) * s);
                v[7] = f2bf((float)(q1.w - 128) * s);
                int sg = scg ^ (r & 7);
                *(short8*)&Bs[r * 64 + sg * 8] = v;
            }
        }
        __syncthreads();

#pragma unroll
        for (int kk = 0; kk < 2; ++kk) {
            short8 a[4], b[4];
            const int aBase = kk ? aOff1 : aOff0;
            const int bBase = kk ? bOff1 : bOff0;
#pragma unroll
            for (int mi = 0; mi < 4; ++mi) a[mi] = *(const short8*)&As[aBase + mi * 16 * 64];
#pragma unroll
            for (int nj = 0; nj < 4; ++nj) b[nj] = *(const short8*)&Bs[bBase + nj * 16 * 64];
#pragma unroll
            for (int mi = 0; mi < 4; ++mi)
#pragma unroll
                for (int nj = 0; nj < 4; ++nj)
                    acc[mi][nj] = __builtin_amdgcn_mfma_f32_16x16x32_bf16(
                        a[mi], b[nj], acc[mi][nj], 0, 0, 0);
        }
        __syncthreads();
    }

#pragma unroll
    for (int nj = 0; nj < 4; ++nj) {
        long col = bn + wn + nj * 16 + l15;
        float bv = bias[col];
#pragma unroll
        for (int mi = 0; mi < 4; ++mi) {
            long row = bm + wm + mi * 16 + q * 4;
#pragma unroll
            for (int r2 = 0; r2 < 4; ++r2)
                out[(row + r2) * (long)N + col] = acc[mi][nj][r2] + bv;
        }
    }
}

// ---------------- launch ----------------

extern "C" void kernel_launch(void* const* d_in, const int* in_sizes, int n_in,
                              void* d_out, int out_size, void* d_ws, size_t ws_size,
                              hipStream_t stream) {
    const float* x      = (const float*)d_in[0];
    const int*   wq     = (const int*)d_in[1];
    const float* scales = (const float*)d_in[2];
    const float* bias   = (const float*)d_in[3];
    float*       out    = (float*)d_out;

    const long N = (long)in_sizes[3];
    const long K = (long)in_sizes[1] / N;
    const long M = (long)in_sizes[0] / K;

    const size_t needW = (size_t)N * K * sizeof(short);
    const size_t needX = (size_t)M * K * sizeof(short);

    short* Wb = (short*)d_ws;
    short* Xb = Wb + (size_t)N * K;

    const bool preB = (d_ws != nullptr) && ws_size >= needW;
    const bool preA = preB && ws_size >= (needW + needX);

    if (preB) {
        long t8 = N * K / 8;
        prepack_w_kernel<<<dim3((unsigned)((t8 + 255) / 256)), dim3(256), 0, stream>>>(
            wq, scales, Wb, t8);
    }
    if (preA) {
        long t8 = M * K / 8;
        prepack_x_kernel<<<dim3((unsigned)((t8 + 255) / 256)), dim3(256), 0, stream>>>(
            x, Xb, t8);
    }

    const long NTl = K / 64;
    const bool big = preA && (M % 256 == 0) && (N % 256 == 0) && (K % 64 == 0) &&
                     (NTl >= 2) && (NTl % 2 == 0);

    if (big) {
        dim3 grid((unsigned)((M / 256) * (N / 256))), block(512);
        gemm256_kernel<<<grid, block, 0, stream>>>(bias, Xb, Wb, out, (int)M, (int)N, (int)K);
    } else {
        dim3 grid((unsigned)((M / 128) * (N / 128))), block(256);
        if (preA)
            gemm_kernel<true, true><<<grid, block, 0, stream>>>(x, wq, scales, bias, Xb, Wb,
                                                                out, (int)M, (int)N, (int)K);
        else if (preB)
            gemm_kernel<false, true><<<grid, block, 0, stream>>>(x, wq, scales, bias, Xb, Wb,
                                                                 out, (int)M, (int)N, (int)K);
        else
            gemm_kernel<false, false><<<grid, block, 0, stream>>>(x, wq, scales, bias, Xb, Wb,
                                                                  out, (int)M, (int)N, (int)K);
    }
}

// Round 8
// 628.088 us; speedup vs baseline: 1.9065x; 1.9065x over previous
//
#include <hip/hip_runtime.h>
#include <hip/hip_bf16.h>

typedef __attribute__((ext_vector_type(8))) short short8;
typedef __attribute__((ext_vector_type(4))) float f32x4;
typedef __attribute__((ext_vector_type(16))) float f32x16;

#define AS1 __attribute__((address_space(1)))
#define AS3 __attribute__((address_space(3)))

static __device__ __forceinline__ short f2bf(float f) {
    __hip_bfloat16 h = __float2bfloat16(f);
    union { __hip_bfloat16 h; short s; } u;
    u.h = h;
    return u.s;
}

// ---------------- prepack kernels ----------------

__global__ __launch_bounds__(256) void prepack_w_kernel(const int* __restrict__ wq,
                                                        const float* __restrict__ scales,
                                                        short* __restrict__ Wb,
                                                        long total8) {
    long i = (long)blockIdx.x * 256 + threadIdx.x;
    if (i >= total8) return;
    const int4* p = (const int4*)wq + i * 2;
    int4 q0 = p[0], q1 = p[1];
    float s = scales[(i * 8) >> 5];
    short8 v;
    v[0] = f2bf((float)(q0.x - 128) * s);
    v[1] = f2bf((float)(q0.y - 128) * s);
    v[2] = f2bf((float)(q0.z - 128) * s);
    v[3] = f2bf((float)(q0.w - 128) * s);
    v[4] = f2bf((float)(q1.x - 128) * s);
    v[5] = f2bf((float)(q1.y - 128) * s);
    v[6] = f2bf((float)(q1.z - 128) * s);
    v[7] = f2bf((float)(q1.w - 128) * s);
    ((short8*)Wb)[i] = v;
}

__global__ __launch_bounds__(256) void prepack_x_kernel(const float* __restrict__ x,
                                                        short* __restrict__ Xb,
                                                        long total8) {
    long i = (long)blockIdx.x * 256 + threadIdx.x;
    if (i >= total8) return;
    const float4* p = (const float4*)x + i * 2;
    float4 f0 = p[0], f1 = p[1];
    short8 v;
    v[0] = f2bf(f0.x); v[1] = f2bf(f0.y); v[2] = f2bf(f0.z); v[3] = f2bf(f0.w);
    v[4] = f2bf(f1.x); v[5] = f2bf(f1.y); v[6] = f2bf(f1.z); v[7] = f2bf(f1.w);
    ((short8*)Xb)[i] = v;
}

// ---------------- 256x256 GEMM, mfma 32x32x16, 2 barriers/K-tile ----------------
// 512 thr = 8 waves (2M x 4N), per-wave C = 128x64 = 4 m-blocks x 2 n-blocks (32x32).
// LDS: A/B each [par*2+half][128x64 bf16], granule(16B) XOR swizzle (slot s holds
// global granule s^(row&7)) -- layout identical to R5; only frag reads changed.
// Per K-tile: ph0 {B all 8 frags + A-s1} ph1 {A-s2, midBAR} ph2 {A-s3} ph3 {drain}.
// A frags double-buffered one k-step ahead; lgkm ledger FIFO-exact (DS-only queue).
// Stage map: A(t+1)@ph0/1 -> par^1; B(t+2)@ph2/3 -> par (safe: all B reads done by
// each wave's WLGN(4)@ph1, ordered vs STGB by mid-barrier).
// vmcnt: VMC(2) at boundary only (lands B(t+1),A(t+1),B(t+2)h0; keeps h1 in flight).
__global__ __launch_bounds__(512, 2)
void gemm256_kernel(const float* __restrict__ bias,
                    const short* __restrict__ Xb, const short* __restrict__ Wb,
                    float* __restrict__ out, int M, int N, int K) {
    __shared__ alignas(16) short As[4 * 8192];
    __shared__ alignas(16) short Bs[4 * 8192];

    const int nM = M >> 8, nN = N >> 8;
    int bid = blockIdx.x;
    {
        int nwg = nM * nN;
        if ((nwg & 7) == 0) bid = (bid & 7) * (nwg >> 3) + (bid >> 3);  // XCD swizzle
    }
    int pm, pn;
    {
        const int G = 8;
        if ((nN % G) == 0) {
            int per = nM * G;
            int grp = bid / per, in = bid % per;
            pn = grp * G + (in % G);
            pm = in / G;
        } else { pn = bid % nN; pm = bid / nN; }
    }

    const int tid  = threadIdx.x;
    const int lane = tid & 63;
    const int wid  = tid >> 6;
    const int wm   = wid >> 2;     // 0..1
    const int wn   = wid & 3;      // 0..3
    const int l31  = lane & 31;
    const int l5   = lane >> 5;    // k-group 0..1
    const int lx   = lane & 7;

    const long bm = (long)pm << 8, bn = (long)pn << 8;
    const long Kl = K;
    const int  NT = K >> 6;

    // A/B slot bases (shorts), parity literal via names
    const int aslot0 = wm * 8192,        aslot1 = (2 + wm) * 8192;
    const int bslot0 = (wn >> 1) * 8192 + ((wn & 1) * 64) * 64;
    const int bslot1 = bslot0 + 2 * 8192;
    const int frow   = l31 * 64;         // row offset within half (shorts)
    // swizzled granule offsets per k-step s: sg = ((2s + l5) ^ (lane&7)) * 8
    const int sgk0 = ((0 + l5) ^ lx) * 8;
    const int sgk1 = ((2 + l5) ^ lx) * 8;
    const int sgk2 = ((4 + l5) ^ lx) * 8;
    const int sgk3 = ((6 + l5) ^ lx) * 8;

    // staging geometry (identical to R5)
    const int chnk    = wid * 1024;
    const int srowrel = wid * 16 + (lane >> 3);
    const int scol    = ((lane & 7) ^ (lane >> 3)) * 8;

    const short* aS00 = Xb + (bm + 0   + srowrel + 0) * Kl + scol;
    const short* aS01 = Xb + (bm + 0   + srowrel + 8) * Kl + scol;
    const short* aS10 = Xb + (bm + 128 + srowrel + 0) * Kl + scol;
    const short* aS11 = Xb + (bm + 128 + srowrel + 8) * Kl + scol;
    const short* bS00 = Wb + (bn + 0   + srowrel + 0) * Kl + scol;
    const short* bS01 = Wb + (bn + 0   + srowrel + 8) * Kl + scol;
    const short* bS10 = Wb + (bn + 128 + srowrel + 0) * Kl + scol;
    const short* bS11 = Wb + (bn + 128 + srowrel + 8) * Kl + scol;

#define STGA(H, PARL, OFF) {                                                          \
    __builtin_amdgcn_global_load_lds((const AS1 void*)(aS##H##0 + (OFF)),             \
        (AS3 void*)&As[((PARL) * 2 + (H)) * 8192 + chnk], 16, 0, 0);                  \
    __builtin_amdgcn_global_load_lds((const AS1 void*)(aS##H##1 + (OFF)),             \
        (AS3 void*)&As[((PARL) * 2 + (H)) * 8192 + chnk + 512], 16, 0, 0); }
#define STGB(H, PARL, OFF) {                                                          \
    __builtin_amdgcn_global_load_lds((const AS1 void*)(bS##H##0 + (OFF)),             \
        (AS3 void*)&Bs[((PARL) * 2 + (H)) * 8192 + chnk], 16, 0, 0);                  \
    __builtin_amdgcn_global_load_lds((const AS1 void*)(bS##H##1 + (OFF)),             \
        (AS3 void*)&Bs[((PARL) * 2 + (H)) * 8192 + chnk + 512], 16, 0, 0); }

// A-frag reads for k-step S into BUF[4] (one per m-block)
#define RDA(BUF, ASLOT, SG) {                                                         \
    BUF[0] = *(const short8*)&As[(ASLOT) + 0 * 2048 + frow + (SG)];                   \
    BUF[1] = *(const short8*)&As[(ASLOT) + 1 * 2048 + frow + (SG)];                   \
    BUF[2] = *(const short8*)&As[(ASLOT) + 2 * 2048 + frow + (SG)];                   \
    BUF[3] = *(const short8*)&As[(ASLOT) + 3 * 2048 + frow + (SG)]; }

// all 8 B frags, s-major (FIFO order matters for the lgkm ledger)
#define LDB_ALL(BSLOT) {                                                              \
    bfr[0][0] = *(const short8*)&Bs[(BSLOT) + 0 * 2048 + frow + sgk0];                \
    bfr[0][1] = *(const short8*)&Bs[(BSLOT) + 1 * 2048 + frow + sgk0];                \
    bfr[1][0] = *(const short8*)&Bs[(BSLOT) + 0 * 2048 + frow + sgk1];                \
    bfr[1][1] = *(const short8*)&Bs[(BSLOT) + 1 * 2048 + frow + sgk1];                \
    bfr[2][0] = *(const short8*)&Bs[(BSLOT) + 0 * 2048 + frow + sgk2];                \
    bfr[2][1] = *(const short8*)&Bs[(BSLOT) + 1 * 2048 + frow + sgk2];                \
    bfr[3][0] = *(const short8*)&Bs[(BSLOT) + 0 * 2048 + frow + sgk3];                \
    bfr[3][1] = *(const short8*)&Bs[(BSLOT) + 1 * 2048 + frow + sgk3]; }

#define MFMA8(S, ABUF) { __builtin_amdgcn_s_setprio(1);                               \
    _Pragma("unroll") for (int mb = 0; mb < 4; ++mb) {                                \
        acc[mb][0] = __builtin_amdgcn_mfma_f32_32x32x16_bf16(                         \
            ABUF[mb], bfr[S][0], acc[mb][0], 0, 0, 0);                                \
        acc[mb][1] = __builtin_amdgcn_mfma_f32_32x32x16_bf16(                         \
            ABUF[mb], bfr[S][1], acc[mb][1], 0, 0, 0); }                              \
    __builtin_amdgcn_s_setprio(0); }

#define BAR  { __builtin_amdgcn_s_barrier(); __builtin_amdgcn_sched_barrier(0); }
#define WLGN(n) { asm volatile("s_waitcnt lgkmcnt(" #n ")" ::: "memory");             \
                  __builtin_amdgcn_sched_barrier(0); }
#define VMC(n)  asm volatile("s_waitcnt vmcnt(" #n ")" ::: "memory")

// One K-tile. ASLOT/BSLOT: this tile's parity slots; NASLOT: next tile's A slot.
// APAR_N: parity literal for STGA dest (t+1); BPAR_T: parity literal for STGB (t+2).
// DO_A/DO_B: stage flags; LAST: final tile (no boundary sync, no next-s0 read).
// DRAIN0: use vmcnt(0) at boundary (pre-final tile).
#define TILE(ASLOT, BSLOT, NASLOT, APAR_N, BPAR_T, OFF_A, OFF_B, DO_A, DO_B, LAST, DRAIN0) { \
    /* ph0 */                                                                         \
    LDB_ALL(BSLOT);                                                                   \
    RDA(akB, ASLOT, sgk1);                                                            \
    if (DO_A) STGA(0, APAR_N, OFF_A);                                                 \
    WLGN(10);                                                                         \
    MFMA8(0, akA);                                                                    \
    /* ph1 */                                                                         \
    RDA(akA, ASLOT, sgk2);                                                            \
    if (DO_A) STGA(1, APAR_N, OFF_A);                                                 \
    WLGN(4);                                                                          \
    MFMA8(1, akB);                                                                    \
    BAR;                                                                              \
    /* ph2 */                                                                         \
    RDA(akB, ASLOT, sgk3);                                                            \
    if (DO_B) STGB(0, BPAR_T, OFF_B);                                                 \
    WLGN(4);                                                                          \
    MFMA8(2, akA);                                                                    \
    /* ph3 */                                                                         \
    if (DO_B) STGB(1, BPAR_T, OFF_B);                                                 \
    WLGN(0);                                                                          \
    MFMA8(3, akB);                                                                    \
    if (!(LAST)) {                                                                    \
        if (DRAIN0) { VMC(0); } else { VMC(2); }                                      \
        BAR;                                                                          \
        RDA(akA, NASLOT, sgk0);                                                       \
    } }

    f32x16 acc[4][2];
#pragma unroll
    for (int mb = 0; mb < 4; ++mb)
#pragma unroll
        for (int nb = 0; nb < 2; ++nb)
#pragma unroll
            for (int r = 0; r < 16; ++r) acc[mb][nb][r] = 0.f;

    short8 akA[4], akB[4], bfr[4][2];

    // ---- prologue: B(0),A(0) -> par0; B(1) -> par1; preload A-s0(0) ----
    STGB(0, 0, 0); STGB(1, 0, 0);
    STGA(0, 0, 0); STGA(1, 0, 0);
    STGB(0, 1, 64); STGB(1, 1, 64);
    VMC(4);                       // B(0),A(0) resident; B(1) in flight
    BAR;
    RDA(akA, aslot0, sgk0);       // 4 lgkm outstanding into tile 0

    // ---- main loop: tiles (t par0, t+1 par1); needs t+3 < NT ----
    for (int t = 0; t + 3 < NT; t += 2) {
        const long o1 = ((long)t + 1) << 6;
        const long o2 = o1 + 64;
        const long o3 = o2 + 64;
        TILE(aslot0, bslot0, aslot1, 1, 0, o1, o2, true, true, false, false);
        TILE(aslot1, bslot1, aslot0, 0, 1, o2, o3, true, true, false, false);
    }
    // ---- final pair (NT-2 par0, NT-1 par1): stage only A(NT-1); drain ----
    {
        const long o1 = ((long)NT - 1) << 6;
        TILE(aslot0, bslot0, aslot1, 1, 0, o1, 0, true, false, false, true);
        TILE(aslot1, bslot1, aslot0, 0, 1, 0, 0, false, false, true, false);
    }

    // ---- epilogue: 32x32 C/D layout col=lane&31, row=(r&3)+8*(r>>2)+4*(lane>>5) ----
#pragma unroll
    for (int nb = 0; nb < 2; ++nb) {
        long col = bn + wn * 64 + nb * 32 + l31;
        float bv = bias[col];
#pragma unroll
        for (int mb = 0; mb < 4; ++mb) {
            long rowb = bm + wm * 128 + mb * 32 + 4 * l5;
#pragma unroll
            for (int r = 0; r < 16; ++r) {
                long row = rowb + (r & 3) + 8 * (r >> 2);
                out[row * (long)N + col] = acc[mb][nb][r] + bv;
            }
        }
    }
#undef STGA
#undef STGB
#undef RDA
#undef LDB_ALL
#undef MFMA8
#undef BAR
#undef WLGN
#undef VMC
#undef TILE
}

// ---------------- fallback 128x128 GEMM (handles fused / odd shapes) ----------------

template <bool PRE_A, bool PRE_B>
__global__ __launch_bounds__(256, 2)
void gemm_kernel(const float* __restrict__ x, const int* __restrict__ wq,
                 const float* __restrict__ scales, const float* __restrict__ bias,
                 const short* __restrict__ Xb, const short* __restrict__ Wb,
                 float* __restrict__ out, int M, int N, int K) {
    constexpr int BM = 128, BN = 128, BK = 64;
    __shared__ alignas(16) short As[BM * BK];
    __shared__ alignas(16) short Bs[BN * BK];

    const int nM = M / BM, nN = N / BN;
    int bid = blockIdx.x;
    int pm, pn;
    const int G = 8;
    if ((nN % G) == 0) {
        int per = nM * G;
        int grp = bid / per;
        int in  = bid % per;
        pn = grp * G + (in % G);
        pm = in / G;
    } else {
        pn = bid % nN;
        pm = bid / nN;
    }

    const int tid  = threadIdx.x;
    const int lane = tid & 63;
    const int wv   = tid >> 6;
    const int wm   = (wv >> 1) * 64;
    const int wn   = (wv & 1) * 64;
    const int q    = lane >> 4;
    const int l15  = lane & 15;
    const int sxor = lane & 7;

    const long bm = (long)pm * BM, bn = (long)pn * BN;

    f32x4 acc[4][4];
#pragma unroll
    for (int i = 0; i < 4; ++i)
#pragma unroll
        for (int j = 0; j < 4; ++j) acc[i][j] = (f32x4){0.f, 0.f, 0.f, 0.f};

    const int srow = tid >> 3;
    const int scg  = tid & 7;

    const int sg0   = q ^ sxor;
    const int aOff0 = (wm + l15) * 64 + sg0 * 8;
    const int aOff1 = (wm + l15) * 64 + (sg0 ^ 4) * 8;
    const int bOff0 = (wn + l15) * 64 + sg0 * 8;
    const int bOff1 = (wn + l15) * 64 + (sg0 ^ 4) * 8;

    const int prRow  = lane >> 3;
    const int prGsrc = (lane & 7) ^ (lane >> 3);

    for (int k0 = 0; k0 < K; k0 += BK) {
        if constexpr (PRE_A) {
#pragma unroll
            for (int i = 0; i < 4; ++i) {
                int r = wv * 32 + i * 8 + prRow;
                const short* src = Xb + (bm + r) * (long)K + k0 + prGsrc * 8;
                __builtin_amdgcn_global_load_lds((const AS1 void*)src,
                                                 (AS3 void*)&As[(wv * 32 + i * 8) * 64],
                                                 16, 0, 0);
            }
        } else {
#pragma unroll
            for (int i = 0; i < 4; ++i) {
                int r = i * 32 + srow;
                const float4* p = (const float4*)(x + (bm + r) * (long)K + k0 + scg * 8);
                float4 f0 = p[0], f1 = p[1];
                short8 v;
                v[0] = f2bf(f0.x); v[1] = f2bf(f0.y); v[2] = f2bf(f0.z); v[3] = f2bf(f0.w);
                v[4] = f2bf(f1.x); v[5] = f2bf(f1.y); v[6] = f2bf(f1.z); v[7] = f2bf(f1.w);
                int sg = scg ^ (r & 7);
                *(short8*)&As[r * 64 + sg * 8] = v;
            }
        }
        if constexpr (PRE_B) {
#pragma unroll
            for (int i = 0; i < 4; ++i) {
                int r = wv * 32 + i * 8 + prRow;
                const short* src = Wb + (bn + r) * (long)K + k0 + prGsrc * 8;
                __builtin_amdgcn_global_load_lds((const AS1 void*)src,
                                                 (AS3 void*)&Bs[(wv * 32 + i * 8) * 64],
                                                 16, 0, 0);
            }
        } else {
#pragma unroll
            for (int i = 0; i < 4; ++i) {
                int r = i * 32 + srow;
                const int4* p = (const int4*)(wq + (bn + r) * (long)K + k0 + scg * 8);
                int4 q0 = p[0], q1 = p[1];
                float s = scales[(bn + r) * (long)(K >> 5) + ((k0 + scg * 8) >> 5)];
                short8 v;
                v[0] = f2bf((float)(q0.x - 128) * s);
                v[1] = f2bf((float)(q0.y - 128) * s);
                v[2] = f2bf((float)(q0.z - 128) * s);
                v[3] = f2bf((float)(q0.w - 128) * s);
                v[4] = f2bf((float)(q1.x - 128) * s);
                v[5] = f2bf((float)(q1.y - 128) * s);
                v[6] = f2bf((float)(q1.z - 128) * s);
                v[7] = f2bf((float)(q1.w - 128) * s);
                int sg = scg ^ (r & 7);
                *(short8*)&Bs[r * 64 + sg * 8] = v;
            }
        }
        __syncthreads();

#pragma unroll
        for (int kk = 0; kk < 2; ++kk) {
            short8 a[4], b[4];
            const int aBase = kk ? aOff1 : aOff0;
            const int bBase = kk ? bOff1 : bOff0;
#pragma unroll
            for (int mi = 0; mi < 4; ++mi) a[mi] = *(const short8*)&As[aBase + mi * 16 * 64];
#pragma unroll
            for (int nj = 0; nj < 4; ++nj) b[nj] = *(const short8*)&Bs[bBase + nj * 16 * 64];
#pragma unroll
            for (int mi = 0; mi < 4; ++mi)
#pragma unroll
                for (int nj = 0; nj < 4; ++nj)
                    acc[mi][nj] = __builtin_amdgcn_mfma_f32_16x16x32_bf16(
                        a[mi], b[nj], acc[mi][nj], 0, 0, 0);
        }
        __syncthreads();
    }

#pragma unroll
    for (int nj = 0; nj < 4; ++nj) {
        long col = bn + wn + nj * 16 + l15;
        float bv = bias[col];
#pragma unroll
        for (int mi = 0; mi < 4; ++mi) {
            long row = bm + wm + mi * 16 + q * 4;
#pragma unroll
            for (int r2 = 0; r2 < 4; ++r2)
                out[(row + r2) * (long)N + col] = acc[mi][nj][r2] + bv;
        }
    }
}

// ---------------- launch ----------------

extern "C" void kernel_launch(void* const* d_in, const int* in_sizes, int n_in,
                              void* d_out, int out_size, void* d_ws, size_t ws_size,
                              hipStream_t stream) {
    const float* x      = (const float*)d_in[0];
    const int*   wq     = (const int*)d_in[1];
    const float* scales = (const float*)d_in[2];
    const float* bias   = (const float*)d_in[3];
    float*       out    = (float*)d_out;

    const long N = (long)in_sizes[3];
    const long K = (long)in_sizes[1] / N;
    const long M = (long)in_sizes[0] / K;

    const size_t needW = (size_t)N * K * sizeof(short);
    const size_t needX = (size_t)M * K * sizeof(short);

    short* Wb = (short*)d_ws;
    short* Xb = Wb + (size_t)N * K;

    const bool preB = (d_ws != nullptr) && ws_size >= needW;
    const bool preA = preB && ws_size >= (needW + needX);

    if (preB) {
        long t8 = N * K / 8;
        prepack_w_kernel<<<dim3((unsigned)((t8 + 255) / 256)), dim3(256), 0, stream>>>(
            wq, scales, Wb, t8);
    }
    if (preA) {
        long t8 = M * K / 8;
        prepack_x_kernel<<<dim3((unsigned)((t8 + 255) / 256)), dim3(256), 0, stream>>>(
            x, Xb, t8);
    }

    const long NTl = K / 64;
    const bool big = preA && (M % 256 == 0) && (N % 256 == 0) && (K % 64 == 0) &&
                     (NTl >= 4) && (NTl % 2 == 0);

    if (big) {
        dim3 grid((unsigned)((M / 256) * (N / 256))), block(512);
        gemm256_kernel<<<grid, block, 0, stream>>>(bias, Xb, Wb, out, (int)M, (int)N, (int)K);
    } else {
        dim3 grid((unsigned)((M / 128) * (N / 128))), block(256);
        if (preA)
            gemm_kernel<true, true><<<grid, block, 0, stream>>>(x, wq, scales, bias, Xb, Wb,
                                                                out, (int)M, (int)N, (int)K);
        else if (preB)
            gemm_kernel<false, true><<<grid, block, 0, stream>>>(x, wq, scales, bias, Xb, Wb,
                                                                 out, (int)M, (int)N, (int)K);
        else
            gemm_kernel<false, false><<<grid, block, 0, stream>>>(x, wq, scales, bias, Xb, Wb,
                                                                  out, (int)M, (int)N, (int)K);
    }
}

// Round 9
// 625.411 us; speedup vs baseline: 1.9147x; 1.0043x over previous
//
#include <hip/hip_runtime.h>
#include <hip/hip_bf16.h>

typedef __attribute__((ext_vector_type(8))) short short8;
typedef __attribute__((ext_vector_type(4))) float f32x4;
typedef __attribute__((ext_vector_type(16))) float f32x16;

#define AS1 __attribute__((address_space(1)))
#define AS3 __attribute__((address_space(3)))

static __device__ __forceinline__ short f2bf(float f) {
    __hip_bfloat16 h = __float2bfloat16(f);
    union { __hip_bfloat16 h; short s; } u;
    u.h = h;
    return u.s;
}

// ---------------- prepack kernels ----------------

__global__ __launch_bounds__(256) void prepack_w_kernel(const int* __restrict__ wq,
                                                        const float* __restrict__ scales,
                                                        short* __restrict__ Wb,
                                                        long total8) {
    long i = (long)blockIdx.x * 256 + threadIdx.x;
    if (i >= total8) return;
    const int4* p = (const int4*)wq + i * 2;
    int4 q0 = p[0], q1 = p[1];
    float s = scales[(i * 8) >> 5];
    short8 v;
    v[0] = f2bf((float)(q0.x - 128) * s);
    v[1] = f2bf((float)(q0.y - 128) * s);
    v[2] = f2bf((float)(q0.z - 128) * s);
    v[3] = f2bf((float)(q0.w - 128) * s);
    v[4] = f2bf((float)(q1.x - 128) * s);
    v[5] = f2bf((float)(q1.y - 128) * s);
    v[6] = f2bf((float)(q1.z - 128) * s);
    v[7] = f2bf((float)(q1.w - 128) * s);
    ((short8*)Wb)[i] = v;
}

__global__ __launch_bounds__(256) void prepack_x_kernel(const float* __restrict__ x,
                                                        short* __restrict__ Xb,
                                                        long total8) {
    long i = (long)blockIdx.x * 256 + threadIdx.x;
    if (i >= total8) return;
    const float4* p = (const float4*)x + i * 2;
    float4 f0 = p[0], f1 = p[1];
    short8 v;
    v[0] = f2bf(f0.x); v[1] = f2bf(f0.y); v[2] = f2bf(f0.z); v[3] = f2bf(f0.w);
    v[4] = f2bf(f1.x); v[5] = f2bf(f1.y); v[6] = f2bf(f1.z); v[7] = f2bf(f1.w);
    ((short8*)Xb)[i] = v;
}

// ---------------- 256x256 GEMM: R5 8-phase structure + mfma 32x32x16 ----------------
// 512 thr = 8 waves (2M x 4N), per-wave C = 128x64 = 4 mb x 2 nb (32x32 blocks).
// LDS: A/B each [par*2+half][128x64 bf16], granule(16B) XOR swizzle (slot g of row r
// holds global granule g^(r&7)). Identical staging/barrier/vmcnt schedule to R5
// (which measured 0 bank conflicts); only fragment reads + MFMA shape changed.
// Per K-tile (4 phases): ph_s reads A-frags for k-step s (4xb128; +B all 8 @ph0),
// stages 1 half-tile, then {BAR; lgkm(0); 8x mfma_32x32x16; BAR}.
// Stage map: A(t+1)@ph0/1 -> par^1; B(t+2)@ph2/3 -> par. VMC(4)@ph3-tail lands
// B(t+1)+A(t+1), keeps B(t+2) in flight (never drains to 0 mid-loop).
__global__ __launch_bounds__(512, 2)
void gemm256_kernel(const float* __restrict__ bias,
                    const short* __restrict__ Xb, const short* __restrict__ Wb,
                    float* __restrict__ out, int M, int N, int K) {
    __shared__ alignas(16) short As[4 * 8192];
    __shared__ alignas(16) short Bs[4 * 8192];

    const int nM = M >> 8, nN = N >> 8;
    int bid = blockIdx.x;
    {
        int nwg = nM * nN;
        if ((nwg & 7) == 0) bid = (bid & 7) * (nwg >> 3) + (bid >> 3);  // XCD swizzle
    }
    int pm, pn;
    {
        const int G = 8;
        if ((nN % G) == 0) {
            int per = nM * G;
            int grp = bid / per, in = bid % per;
            pn = grp * G + (in % G);
            pm = in / G;
        } else { pn = bid % nN; pm = bid / nN; }
    }

    const int tid  = threadIdx.x;
    const int lane = tid & 63;
    const int wid  = tid >> 6;
    const int wm   = wid >> 2;     // 0..1
    const int wn   = wid & 3;      // 0..3
    const int l31  = lane & 31;
    const int l5   = lane >> 5;    // k-subgroup 0..1
    const int lx   = lane & 7;

    const long bm = (long)pm << 8, bn = (long)pn << 8;
    const long Kl = K;
    const int  NT = K >> 6;

    // A/B slot bases (shorts); parity literal via two names
    const int aslot0 = wm * 8192,        aslot1 = (2 + wm) * 8192;
    const int bslot0 = (wn >> 1) * 8192 + ((wn & 1) * 64) * 64;
    const int bslot1 = bslot0 + 2 * 8192;
    const int frow   = l31 * 64;
    // swizzled granule offset for k-step s: ((2s + l5) ^ lx) * 8
    const int sgk0 = ((0 + l5) ^ lx) * 8;
    const int sgk1 = ((2 + l5) ^ lx) * 8;
    const int sgk2 = ((4 + l5) ^ lx) * 8;
    const int sgk3 = ((6 + l5) ^ lx) * 8;

    // staging geometry (identical to R5/R8)
    const int chnk    = wid * 1024;
    const int srowrel = wid * 16 + (lane >> 3);
    const int scol    = ((lane & 7) ^ (lane >> 3)) * 8;

    const short* aS00 = Xb + (bm + 0   + srowrel + 0) * Kl + scol;
    const short* aS01 = Xb + (bm + 0   + srowrel + 8) * Kl + scol;
    const short* aS10 = Xb + (bm + 128 + srowrel + 0) * Kl + scol;
    const short* aS11 = Xb + (bm + 128 + srowrel + 8) * Kl + scol;
    const short* bS00 = Wb + (bn + 0   + srowrel + 0) * Kl + scol;
    const short* bS01 = Wb + (bn + 0   + srowrel + 8) * Kl + scol;
    const short* bS10 = Wb + (bn + 128 + srowrel + 0) * Kl + scol;
    const short* bS11 = Wb + (bn + 128 + srowrel + 8) * Kl + scol;

#define STGA(H, PARL, OFF) {                                                          \
    __builtin_amdgcn_global_load_lds((const AS1 void*)(aS##H##0 + (OFF)),             \
        (AS3 void*)&As[((PARL) * 2 + (H)) * 8192 + chnk], 16, 0, 0);                  \
    __builtin_amdgcn_global_load_lds((const AS1 void*)(aS##H##1 + (OFF)),             \
        (AS3 void*)&As[((PARL) * 2 + (H)) * 8192 + chnk + 512], 16, 0, 0); }
#define STGB(H, PARL, OFF) {                                                          \
    __builtin_amdgcn_global_load_lds((const AS1 void*)(bS##H##0 + (OFF)),             \
        (AS3 void*)&Bs[((PARL) * 2 + (H)) * 8192 + chnk], 16, 0, 0);                  \
    __builtin_amdgcn_global_load_lds((const AS1 void*)(bS##H##1 + (OFF)),             \
        (AS3 void*)&Bs[((PARL) * 2 + (H)) * 8192 + chnk + 512], 16, 0, 0); }

// A-frag reads for one k-step (4 m-blocks)
#define RDA(ASLOT, SG) {                                                              \
    ak[0] = *(const short8*)&As[(ASLOT) + 0 * 2048 + frow + (SG)];                    \
    ak[1] = *(const short8*)&As[(ASLOT) + 1 * 2048 + frow + (SG)];                    \
    ak[2] = *(const short8*)&As[(ASLOT) + 2 * 2048 + frow + (SG)];                    \
    ak[3] = *(const short8*)&As[(ASLOT) + 3 * 2048 + frow + (SG)]; }

// all 8 B frags for the tile (2 nb x 4 k-steps)
#define LDB_ALL(BSLOT) {                                                              \
    bfr[0][0] = *(const short8*)&Bs[(BSLOT) + 0 * 2048 + frow + sgk0];                \
    bfr[0][1] = *(const short8*)&Bs[(BSLOT) + 1 * 2048 + frow + sgk0];                \
    bfr[1][0] = *(const short8*)&Bs[(BSLOT) + 0 * 2048 + frow + sgk1];                \
    bfr[1][1] = *(const short8*)&Bs[(BSLOT) + 1 * 2048 + frow + sgk1];                \
    bfr[2][0] = *(const short8*)&Bs[(BSLOT) + 0 * 2048 + frow + sgk2];                \
    bfr[2][1] = *(const short8*)&Bs[(BSLOT) + 1 * 2048 + frow + sgk2];                \
    bfr[3][0] = *(const short8*)&Bs[(BSLOT) + 0 * 2048 + frow + sgk3];                \
    bfr[3][1] = *(const short8*)&Bs[(BSLOT) + 1 * 2048 + frow + sgk3]; }

#define MFMA8(S) { __builtin_amdgcn_s_setprio(1);                                     \
    _Pragma("unroll") for (int mb = 0; mb < 4; ++mb) {                                \
        acc[mb][0] = __builtin_amdgcn_mfma_f32_32x32x16_bf16(                         \
            ak[mb], bfr[S][0], acc[mb][0], 0, 0, 0);                                  \
        acc[mb][1] = __builtin_amdgcn_mfma_f32_32x32x16_bf16(                         \
            ak[mb], bfr[S][1], acc[mb][1], 0, 0, 0); }                                \
    __builtin_amdgcn_s_setprio(0); }

#define BAR  __builtin_amdgcn_s_barrier()
#define WLGN(n) { asm volatile("s_waitcnt lgkmcnt(" #n ")" ::: "memory");             \
                  __builtin_amdgcn_sched_barrier(0); }
#define VMC(n)  asm volatile("s_waitcnt vmcnt(" #n ")" ::: "memory")

// One K-tile, R5 phase skeleton. ASLOT/BSLOT: this tile's slots. APAR_N/BPAR_T:
// stage-dest parity literals. LAST: no trailing sync. DRAIN0: vmcnt(0) at tail.
#define TILE32(ASLOT, BSLOT, APAR_N, BPAR_T, OFF_A, OFF_B, DO_A, DO_B, LAST, DRAIN0) { \
    /* ph0 */                                                                         \
    RDA(ASLOT, sgk0); LDB_ALL(BSLOT);                                                 \
    if (DO_A) STGA(0, APAR_N, OFF_A);                                                 \
    WLGN(8); BAR; WLGN(0); MFMA8(0); BAR;                                             \
    /* ph1 */                                                                         \
    RDA(ASLOT, sgk1);                                                                 \
    if (DO_A) STGA(1, APAR_N, OFF_A);                                                 \
    BAR; WLGN(0); MFMA8(1); BAR;                                                      \
    /* ph2 */                                                                         \
    RDA(ASLOT, sgk2);                                                                 \
    if (DO_B) STGB(0, BPAR_T, OFF_B);                                                 \
    BAR; WLGN(0); MFMA8(2); BAR;                                                      \
    /* ph3 */                                                                         \
    RDA(ASLOT, sgk3);                                                                 \
    if (DO_B) STGB(1, BPAR_T, OFF_B);                                                 \
    BAR; WLGN(0); MFMA8(3);                                                           \
    if (!(LAST)) {                                                                    \
        if (DRAIN0) { VMC(0); } else { VMC(4); }                                      \
        BAR;                                                                          \
    } }

    f32x16 acc[4][2];
#pragma unroll
    for (int mb = 0; mb < 4; ++mb)
#pragma unroll
        for (int nb = 0; nb < 2; ++nb)
#pragma unroll
            for (int r = 0; r < 16; ++r) acc[mb][nb][r] = 0.f;

    short8 ak[4], bfr[4][2];

    // ---- prologue: B(0),A(0) -> par0; B(1) -> par1; keep B(1) in flight ----
    STGB(0, 0, 0); STGB(1, 0, 0);
    STGA(0, 0, 0); STGA(1, 0, 0);
    STGB(0, 1, 64); STGB(1, 1, 64);
    VMC(4);
    BAR;

    // ---- main loop: tiles (t par0, t+1 par1); needs t+3 < NT ----
    for (int t = 0; t + 3 < NT; t += 2) {
        const long o1 = ((long)t + 1) << 6;
        const long o2 = o1 + 64;
        const long o3 = o2 + 64;
        TILE32(aslot0, bslot0, 1, 0, o1, o2, true, true, false, false);
        TILE32(aslot1, bslot1, 0, 1, o2, o3, true, true, false, false);
    }
    // ---- final pair (NT-2 par0, NT-1 par1): stage only A(NT-1); drain ----
    {
        const long o1 = ((long)NT - 1) << 6;
        TILE32(aslot0, bslot0, 1, 0, o1, 0, true, false, false, true);
        TILE32(aslot1, bslot1, 0, 1, 0, 0, false, false, true, false);
    }

    // ---- epilogue: 32x32 C/D layout col=lane&31, row=(r&3)+8*(r>>2)+4*(lane>>5) ----
#pragma unroll
    for (int nb = 0; nb < 2; ++nb) {
        long col = bn + wn * 64 + nb * 32 + l31;
        float bv = bias[col];
#pragma unroll
        for (int mb = 0; mb < 4; ++mb) {
            long rowb = bm + wm * 128 + mb * 32 + 4 * l5;
#pragma unroll
            for (int r = 0; r < 16; ++r) {
                long row = rowb + (r & 3) + 8 * (r >> 2);
                out[row * (long)N + col] = acc[mb][nb][r] + bv;
            }
        }
    }
#undef STGA
#undef STGB
#undef RDA
#undef LDB_ALL
#undef MFMA8
#undef BAR
#undef WLGN
#undef VMC
#undef TILE32
}

// ---------------- fallback 128x128 GEMM (handles fused / odd shapes) ----------------

template <bool PRE_A, bool PRE_B>
__global__ __launch_bounds__(256, 2)
void gemm_kernel(const float* __restrict__ x, const int* __restrict__ wq,
                 const float* __restrict__ scales, const float* __restrict__ bias,
                 const short* __restrict__ Xb, const short* __restrict__ Wb,
                 float* __restrict__ out, int M, int N, int K) {
    constexpr int BM = 128, BN = 128, BK = 64;
    __shared__ alignas(16) short As[BM * BK];
    __shared__ alignas(16) short Bs[BN * BK];

    const int nM = M / BM, nN = N / BN;
    int bid = blockIdx.x;
    int pm, pn;
    const int G = 8;
    if ((nN % G) == 0) {
        int per = nM * G;
        int grp = bid / per;
        int in  = bid % per;
        pn = grp * G + (in % G);
        pm = in / G;
    } else {
        pn = bid % nN;
        pm = bid / nN;
    }

    const int tid  = threadIdx.x;
    const int lane = tid & 63;
    const int wv   = tid >> 6;
    const int wm   = (wv >> 1) * 64;
    const int wn   = (wv & 1) * 64;
    const int q    = lane >> 4;
    const int l15  = lane & 15;
    const int sxor = lane & 7;

    const long bm = (long)pm * BM, bn = (long)pn * BN;

    f32x4 acc[4][4];
#pragma unroll
    for (int i = 0; i < 4; ++i)
#pragma unroll
        for (int j = 0; j < 4; ++j) acc[i][j] = (f32x4){0.f, 0.f, 0.f, 0.f};

    const int srow = tid >> 3;
    const int scg  = tid & 7;

    const int sg0   = q ^ sxor;
    const int aOff0 = (wm + l15) * 64 + sg0 * 8;
    const int aOff1 = (wm + l15) * 64 + (sg0 ^ 4) * 8;
    const int bOff0 = (wn + l15) * 64 + sg0 * 8;
    const int bOff1 = (wn + l15) * 64 + (sg0 ^ 4) * 8;

    const int prRow  = lane >> 3;
    const int prGsrc = (lane & 7) ^ (lane >> 3);

    for (int k0 = 0; k0 < K; k0 += BK) {
        if constexpr (PRE_A) {
#pragma unroll
            for (int i = 0; i < 4; ++i) {
                int r = wv * 32 + i * 8 + prRow;
                const short* src = Xb + (bm + r) * (long)K + k0 + prGsrc * 8;
                __builtin_amdgcn_global_load_lds((const AS1 void*)src,
                                                 (AS3 void*)&As[(wv * 32 + i * 8) * 64],
                                                 16, 0, 0);
            }
        } else {
#pragma unroll
            for (int i = 0; i < 4; ++i) {
                int r = i * 32 + srow;
                const float4* p = (const float4*)(x + (bm + r) * (long)K + k0 + scg * 8);
                float4 f0 = p[0], f1 = p[1];
                short8 v;
                v[0] = f2bf(f0.x); v[1] = f2bf(f0.y); v[2] = f2bf(f0.z); v[3] = f2bf(f0.w);
                v[4] = f2bf(f1.x); v[5] = f2bf(f1.y); v[6] = f2bf(f1.z); v[7] = f2bf(f1.w);
                int sg = scg ^ (r & 7);
                *(short8*)&As[r * 64 + sg * 8] = v;
            }
        }
        if constexpr (PRE_B) {
#pragma unroll
            for (int i = 0; i < 4; ++i) {
                int r = wv * 32 + i * 8 + prRow;
                const short* src = Wb + (bn + r) * (long)K + k0 + prGsrc * 8;
                __builtin_amdgcn_global_load_lds((const AS1 void*)src,
                                                 (AS3 void*)&Bs[(wv * 32 + i * 8) * 64],
                                                 16, 0, 0);
            }
        } else {
#pragma unroll
            for (int i = 0; i < 4; ++i) {
                int r = i * 32 + srow;
                const int4* p = (const int4*)(wq + (bn + r) * (long)K + k0 + scg * 8);
                int4 q0 = p[0], q1 = p[1];
                float s = scales[(bn + r) * (long)(K >> 5) + ((k0 + scg * 8) >> 5)];
                short8 v;
                v[0] = f2bf((float)(q0.x - 128) * s);
                v[1] = f2bf((float)(q0.y - 128) * s);
                v[2] = f2bf((float)(q0.z - 128) * s);
                v[3] = f2bf((float)(q0.w - 128) * s);
                v[4] = f2bf((float)(q1.x - 128) * s);
                v[5] = f2bf((float)(q1.y - 128) * s);
                v[6] = f2bf((float)(q1.z - 128) * s);
                v[7] = f2bf((float)(q1.w - 128) * s);
                int sg = scg ^ (r & 7);
                *(short8*)&Bs[r * 64 + sg * 8] = v;
            }
        }
        __syncthreads();

#pragma unroll
        for (int kk = 0; kk < 2; ++kk) {
            short8 a[4], b[4];
            const int aBase = kk ? aOff1 : aOff0;
            const int bBase = kk ? bOff1 : bOff0;
#pragma unroll
            for (int mi = 0; mi < 4; ++mi) a[mi] = *(const short8*)&As[aBase + mi * 16 * 64];
#pragma unroll
            for (int nj = 0; nj < 4; ++nj) b[nj] = *(const short8*)&Bs[bBase + nj * 16 * 64];
#pragma unroll
            for (int mi = 0; mi < 4; ++mi)
#pragma unroll
                for (int nj = 0; nj < 4; ++nj)
                    acc[mi][nj] = __builtin_amdgcn_mfma_f32_16x16x32_bf16(
                        a[mi], b[nj], acc[mi][nj], 0, 0, 0);
        }
        __syncthreads();
    }

#pragma unroll
    for (int nj = 0; nj < 4; ++nj) {
        long col = bn + wn + nj * 16 + l15;
        float bv = bias[col];
#pragma unroll
        for (int mi = 0; mi < 4; ++mi) {
            long row = bm + wm + mi * 16 + q * 4;
#pragma unroll
            for (int r2 = 0; r2 < 4; ++r2)
                out[(row + r2) * (long)N + col] = acc[mi][nj][r2] + bv;
        }
    }
}

// ---------------- launch ----------------

extern "C" void kernel_launch(void* const* d_in, const int* in_sizes, int n_in,
                              void* d_out, int out_size, void* d_ws, size_t ws_size,
                              hipStream_t stream) {
    const float* x      = (const float*)d_in[0];
    const int*   wq     = (const int*)d_in[1];
    const float* scales = (const float*)d_in[2];
    const float* bias   = (const float*)d_in[3];
    float*       out    = (float*)d_out;

    const long N = (long)in_sizes[3];
    const long K = (long)in_sizes[1] / N;
    const long M = (long)in_sizes[0] / K;

    const size_t needW = (size_t)N * K * sizeof(short);
    const size_t needX = (size_t)M * K * sizeof(short);

    short* Wb = (short*)d_ws;
    short* Xb = Wb + (size_t)N * K;

    const bool preB = (d_ws != nullptr) && ws_size >= needW;
    const bool preA = preB && ws_size >= (needW + needX);

    if (preB) {
        long t8 = N * K / 8;
        prepack_w_kernel<<<dim3((unsigned)((t8 + 255) / 256)), dim3(256), 0, stream>>>(
            wq, scales, Wb, t8);
    }
    if (preA) {
        long t8 = M * K / 8;
        prepack_x_kernel<<<dim3((unsigned)((t8 + 255) / 256)), dim3(256), 0, stream>>>(
            x, Xb, t8);
    }

    const long NTl = K / 64;
    const bool big = preA && (M % 256 == 0) && (N % 256 == 0) && (K % 64 == 0) &&
                     (NTl >= 4) && (NTl % 2 == 0);

    if (big) {
        dim3 grid((unsigned)((M / 256) * (N / 256))), block(512);
        gemm256_kernel<<<grid, block, 0, stream>>>(bias, Xb, Wb, out, (int)M, (int)N, (int)K);
    } else {
        dim3 grid((unsigned)((M / 128) * (N / 128))), block(256);
        if (preA)
            gemm_kernel<true, true><<<grid, block, 0, stream>>>(x, wq, scales, bias, Xb, Wb,
                                                                out, (int)M, (int)N, (int)K);
        else if (preB)
            gemm_kernel<false, true><<<grid, block, 0, stream>>>(x, wq, scales, bias, Xb, Wb,
                                                                 out, (int)M, (int)N, (int)K);
        else
            gemm_kernel<false, false><<<grid, block, 0, stream>>>(x, wq, scales, bias, Xb, Wb,
                                                                  out, (int)M, (int)N, (int)K);
    }
}

// Round 10
// 600.646 us; speedup vs baseline: 1.9936x; 1.0412x over previous
//
#include <hip/hip_runtime.h>
#include <hip/hip_bf16.h>

typedef __attribute__((ext_vector_type(8))) short short8;
typedef __attribute__((ext_vector_type(4))) float f32x4;

#define AS1 __attribute__((address_space(1)))
#define AS3 __attribute__((address_space(3)))

static __device__ __forceinline__ short f2bf(float f) {
    __hip_bfloat16 h = __float2bfloat16(f);
    union { __hip_bfloat16 h; short s; } u;
    u.h = h;
    return u.s;
}

// ---------------- prepack kernels ----------------

__global__ __launch_bounds__(256) void prepack_w_kernel(const int* __restrict__ wq,
                                                        const float* __restrict__ scales,
                                                        short* __restrict__ Wb,
                                                        long total8) {
    long i = (long)blockIdx.x * 256 + threadIdx.x;
    if (i >= total8) return;
    const int4* p = (const int4*)wq + i * 2;
    int4 q0 = p[0], q1 = p[1];
    float s = scales[(i * 8) >> 5];
    short8 v;
    v[0] = f2bf((float)(q0.x - 128) * s);
    v[1] = f2bf((float)(q0.y - 128) * s);
    v[2] = f2bf((float)(q0.z - 128) * s);
    v[3] = f2bf((float)(q0.w - 128) * s);
    v[4] = f2bf((float)(q1.x - 128) * s);
    v[5] = f2bf((float)(q1.y - 128) * s);
    v[6] = f2bf((float)(q1.z - 128) * s);
    v[7] = f2bf((float)(q1.w - 128) * s);
    ((short8*)Wb)[i] = v;
}

__global__ __launch_bounds__(256) void prepack_x_kernel(const float* __restrict__ x,
                                                        short* __restrict__ Xb,
                                                        long total8) {
    long i = (long)blockIdx.x * 256 + threadIdx.x;
    if (i >= total8) return;
    const float4* p = (const float4*)x + i * 2;
    float4 f0 = p[0], f1 = p[1];
    short8 v;
    v[0] = f2bf(f0.x); v[1] = f2bf(f0.y); v[2] = f2bf(f0.z); v[3] = f2bf(f0.w);
    v[4] = f2bf(f1.x); v[5] = f2bf(f1.y); v[6] = f2bf(f1.z); v[7] = f2bf(f1.w);
    ((short8*)Xb)[i] = v;
}

// ---------------- 256x256 GEMM: 16x16x32 MFMA, 2 phases / K-tile ----------------
// 512 thr = 8 waves (2M x 4N), per-wave C = 128x64 (8 m-frags x 4 n-frags), BK=64.
// LDS: A/B each [par*2+half][128x64 bf16], granule(16B) XOR swizzle (R5's proven
// 0-conflict mapping). Phase = one k-step (k=32): 32 MFMA after B(8)+A(8) reads.
//   ph0: {LDB8 + RDA8(s0); stage A0(t+1); lgkm(8); BAR; lgkm(0); MFMA32(s0); BAR}
//   ph1: {RDA8(s1); stage A1(t+1),B0(t+2),B1(t+2); BAR; lgkm(0); MFMA32(s1);
//         VMC(4); BAR}
// WAR audit: B(t+2)->par0 issues at ph1, after ph0-exit barrier => all waves' B(t)
// reads (lgkm-complete before their ph0 barrier) are done. A(t+1)->par1 last read
// at tile t-1 (barrier-separated). vmcnt ledger at boundary: B(t+1)4 + A(t+1)4 +
// B(t+2)4 = 12 -> VMC(4) lands the 8 needed, keeps B(t+2) in flight.
__global__ __launch_bounds__(512, 2)
void gemm256_kernel(const float* __restrict__ bias,
                    const short* __restrict__ Xb, const short* __restrict__ Wb,
                    float* __restrict__ out, int M, int N, int K) {
    __shared__ alignas(16) short As[4 * 8192];
    __shared__ alignas(16) short Bs[4 * 8192];

    const int nM = M >> 8, nN = N >> 8;
    int bid = blockIdx.x;
    {
        int nwg = nM * nN;
        if ((nwg & 7) == 0) bid = (bid & 7) * (nwg >> 3) + (bid >> 3);  // XCD swizzle
    }
    int pm, pn;
    {
        const int G = 8;
        if ((nN % G) == 0) {
            int per = nM * G;
            int grp = bid / per, in = bid % per;
            pn = grp * G + (in % G);
            pm = in / G;
        } else { pn = bid % nN; pm = bid / nN; }
    }

    const int tid  = threadIdx.x;
    const int lane = tid & 63;
    const int wid  = tid >> 6;
    const int wm   = wid >> 2;     // 0..1
    const int wn   = wid & 3;      // 0..3
    const int q4   = lane >> 4;
    const int l15  = lane & 15;
    const int lx   = lane & 7;

    const long bm = (long)pm << 8, bn = (long)pn << 8;
    const long Kl = K;
    const int  NT = K >> 6;

    // A/B read bases per parity (shorts); R5's exact conflict-free pattern
    const int rA0 = wm * 8192 + l15 * 64;
    const int rA1 = (2 + wm) * 8192 + l15 * 64;
    const int rB0 = (wn >> 1) * 8192 + ((wn & 1) * 64 + l15) * 64;
    const int rB1 = rB0 + 2 * 8192;
    const int sg0 = (q4 ^ lx) * 8;        // k-step 0 granule (swizzled)
    const int sg1 = ((4 + q4) ^ lx) * 8;  // k-step 1

    // staging geometry (identical to R5)
    const int chnk    = wid * 1024;
    const int srowrel = wid * 16 + (lane >> 3);
    const int scol    = ((lane & 7) ^ (lane >> 3)) * 8;

    const short* aS00 = Xb + (bm + 0   + srowrel + 0) * Kl + scol;
    const short* aS01 = Xb + (bm + 0   + srowrel + 8) * Kl + scol;
    const short* aS10 = Xb + (bm + 128 + srowrel + 0) * Kl + scol;
    const short* aS11 = Xb + (bm + 128 + srowrel + 8) * Kl + scol;
    const short* bS00 = Wb + (bn + 0   + srowrel + 0) * Kl + scol;
    const short* bS01 = Wb + (bn + 0   + srowrel + 8) * Kl + scol;
    const short* bS10 = Wb + (bn + 128 + srowrel + 0) * Kl + scol;
    const short* bS11 = Wb + (bn + 128 + srowrel + 8) * Kl + scol;

#define STGA(H, PARL, OFF) {                                                          \
    __builtin_amdgcn_global_load_lds((const AS1 void*)(aS##H##0 + (OFF)),             \
        (AS3 void*)&As[((PARL) * 2 + (H)) * 8192 + chnk], 16, 0, 0);                  \
    __builtin_amdgcn_global_load_lds((const AS1 void*)(aS##H##1 + (OFF)),             \
        (AS3 void*)&As[((PARL) * 2 + (H)) * 8192 + chnk + 512], 16, 0, 0); }
#define STGB(H, PARL, OFF) {                                                          \
    __builtin_amdgcn_global_load_lds((const AS1 void*)(bS##H##0 + (OFF)),             \
        (AS3 void*)&Bs[((PARL) * 2 + (H)) * 8192 + chnk], 16, 0, 0);                  \
    __builtin_amdgcn_global_load_lds((const AS1 void*)(bS##H##1 + (OFF)),             \
        (AS3 void*)&Bs[((PARL) * 2 + (H)) * 8192 + chnk + 512], 16, 0, 0); }

// all 8 A m-frags for one k-step
#define RDA8(RA, SG) {                                                                \
    ak[0] = *(const short8*)&As[(RA) + 0 * 1024 + (SG)];                              \
    ak[1] = *(const short8*)&As[(RA) + 1 * 1024 + (SG)];                              \
    ak[2] = *(const short8*)&As[(RA) + 2 * 1024 + (SG)];                              \
    ak[3] = *(const short8*)&As[(RA) + 3 * 1024 + (SG)];                              \
    ak[4] = *(const short8*)&As[(RA) + 4 * 1024 + (SG)];                              \
    ak[5] = *(const short8*)&As[(RA) + 5 * 1024 + (SG)];                              \
    ak[6] = *(const short8*)&As[(RA) + 6 * 1024 + (SG)];                              \
    ak[7] = *(const short8*)&As[(RA) + 7 * 1024 + (SG)]; }

// all 8 B frags (4 n x 2 k-steps), issued B-first for the lgkm(8) ledger
#define LDB8(RB) { _Pragma("unroll") for (int n = 0; n < 4; ++n) {                    \
    bfr[n][0] = *(const short8*)&Bs[(RB) + n * 1024 + sg0];                           \
    bfr[n][1] = *(const short8*)&Bs[(RB) + n * 1024 + sg1]; } }

#define MFMA32(KK) { __builtin_amdgcn_s_setprio(1);                                   \
    _Pragma("unroll") for (int mi = 0; mi < 8; ++mi)                                  \
        _Pragma("unroll") for (int n = 0; n < 4; ++n)                                 \
            acc[mi][n] = __builtin_amdgcn_mfma_f32_16x16x32_bf16(                     \
                ak[mi], bfr[n][KK], acc[mi][n], 0, 0, 0);                             \
    __builtin_amdgcn_s_setprio(0); }

#define BAR  __builtin_amdgcn_s_barrier()
#define WLGN(n) { asm volatile("s_waitcnt lgkmcnt(" #n ")" ::: "memory");             \
                  __builtin_amdgcn_sched_barrier(0); }
#define VMC(n)  asm volatile("s_waitcnt vmcnt(" #n ")" ::: "memory")

// One K-tile, 2 phases. RA/RB: this tile's slots. APAR_N/BPAR_T: stage-dest parity.
#define TILE2(RA, RB, APAR_N, BPAR_T, OFF_A, OFF_B, DO_A, DO_B, LAST, DRAIN0) {       \
    /* ph0: k-step 0 */                                                               \
    LDB8(RB);                                                                         \
    RDA8(RA, sg0);                                                                    \
    if (DO_A) STGA(0, APAR_N, OFF_A);                                                 \
    WLGN(8); BAR; WLGN(0);                                                            \
    MFMA32(0);                                                                        \
    BAR;                                                                              \
    /* ph1: k-step 1 */                                                               \
    RDA8(RA, sg1);                                                                    \
    if (DO_A) STGA(1, APAR_N, OFF_A);                                                 \
    if (DO_B) { STGB(0, BPAR_T, OFF_B); STGB(1, BPAR_T, OFF_B); }                     \
    BAR; WLGN(0);                                                                     \
    MFMA32(1);                                                                        \
    if (!(LAST)) {                                                                    \
        if (DRAIN0) { VMC(0); } else { VMC(4); }                                      \
        BAR;                                                                          \
    } }

    f32x4 acc[8][4];
#pragma unroll
    for (int m = 0; m < 8; ++m)
#pragma unroll
        for (int n = 0; n < 4; ++n) acc[m][n] = (f32x4){0.f, 0.f, 0.f, 0.f};

    short8 ak[8], bfr[4][2];

    // ---- prologue: B(0),A(0) -> par0; B(1) -> par1; keep B(1) in flight ----
    STGB(0, 0, 0); STGB(1, 0, 0);
    STGA(0, 0, 0); STGA(1, 0, 0);
    STGB(0, 1, 64); STGB(1, 1, 64);
    VMC(4);
    BAR;

    // ---- main loop: tiles (t par0, t+1 par1); needs t+3 < NT ----
    for (int t = 0; t + 3 < NT; t += 2) {
        const long o1 = ((long)t + 1) << 6;
        const long o2 = o1 + 64;
        const long o3 = o2 + 64;
        TILE2(rA0, rB0, 1, 0, o1, o2, true, true, false, false);
        TILE2(rA1, rB1, 0, 1, o2, o3, true, true, false, false);
    }
    // ---- final pair (NT-2 par0, NT-1 par1): stage only A(NT-1); drain ----
    {
        const long o1 = ((long)NT - 1) << 6;
        TILE2(rA0, rB0, 1, 0, o1, 0, true, false, false, true);
        TILE2(rA1, rB1, 0, 1, 0, 0, false, false, true, false);
    }

    // ---- epilogue: C/D layout col = lane&15, row = (lane>>4)*4 + reg ----
#pragma unroll
    for (int n = 0; n < 4; ++n) {
        long col = bn + wn * 64 + n * 16 + l15;
        float bv = bias[col];
#pragma unroll
        for (int m = 0; m < 8; ++m) {
            long row = bm + wm * 128 + m * 16 + q4 * 4;
#pragma unroll
            for (int r = 0; r < 4; ++r)
                out[(row + r) * (long)N + col] = acc[m][n][r] + bv;
        }
    }
#undef STGA
#undef STGB
#undef RDA8
#undef LDB8
#undef MFMA32
#undef BAR
#undef WLGN
#undef VMC
#undef TILE2
}

// ---------------- fallback 128x128 GEMM (handles fused / odd shapes) ----------------

template <bool PRE_A, bool PRE_B>
__global__ __launch_bounds__(256, 2)
void gemm_kernel(const float* __restrict__ x, const int* __restrict__ wq,
                 const float* __restrict__ scales, const float* __restrict__ bias,
                 const short* __restrict__ Xb, const short* __restrict__ Wb,
                 float* __restrict__ out, int M, int N, int K) {
    constexpr int BM = 128, BN = 128, BK = 64;
    __shared__ alignas(16) short As[BM * BK];
    __shared__ alignas(16) short Bs[BN * BK];

    const int nM = M / BM, nN = N / BN;
    int bid = blockIdx.x;
    int pm, pn;
    const int G = 8;
    if ((nN % G) == 0) {
        int per = nM * G;
        int grp = bid / per;
        int in  = bid % per;
        pn = grp * G + (in % G);
        pm = in / G;
    } else {
        pn = bid % nN;
        pm = bid / nN;
    }

    const int tid  = threadIdx.x;
    const int lane = tid & 63;
    const int wv   = tid >> 6;
    const int wm   = (wv >> 1) * 64;
    const int wn   = (wv & 1) * 64;
    const int q    = lane >> 4;
    const int l15  = lane & 15;
    const int sxor = lane & 7;

    const long bm = (long)pm * BM, bn = (long)pn * BN;

    f32x4 acc[4][4];
#pragma unroll
    for (int i = 0; i < 4; ++i)
#pragma unroll
        for (int j = 0; j < 4; ++j) acc[i][j] = (f32x4){0.f, 0.f, 0.f, 0.f};

    const int srow = tid >> 3;
    const int scg  = tid & 7;

    const int sg0   = q ^ sxor;
    const int aOff0 = (wm + l15) * 64 + sg0 * 8;
    const int aOff1 = (wm + l15) * 64 + (sg0 ^ 4) * 8;
    const int bOff0 = (wn + l15) * 64 + sg0 * 8;
    const int bOff1 = (wn + l15) * 64 + (sg0 ^ 4) * 8;

    const int prRow  = lane >> 3;
    const int prGsrc = (lane & 7) ^ (lane >> 3);

    for (int k0 = 0; k0 < K; k0 += BK) {
        if constexpr (PRE_A) {
#pragma unroll
            for (int i = 0; i < 4; ++i) {
                int r = wv * 32 + i * 8 + prRow;
                const short* src = Xb + (bm + r) * (long)K + k0 + prGsrc * 8;
                __builtin_amdgcn_global_load_lds((const AS1 void*)src,
                                                 (AS3 void*)&As[(wv * 32 + i * 8) * 64],
                                                 16, 0, 0);
            }
        } else {
#pragma unroll
            for (int i = 0; i < 4; ++i) {
                int r = i * 32 + srow;
                const float4* p = (const float4*)(x + (bm + r) * (long)K + k0 + scg * 8);
                float4 f0 = p[0], f1 = p[1];
                short8 v;
                v[0] = f2bf(f0.x); v[1] = f2bf(f0.y); v[2] = f2bf(f0.z); v[3] = f2bf(f0.w);
                v[4] = f2bf(f1.x); v[5] = f2bf(f1.y); v[6] = f2bf(f1.z); v[7] = f2bf(f1.w);
                int sg = scg ^ (r & 7);
                *(short8*)&As[r * 64 + sg * 8] = v;
            }
        }
        if constexpr (PRE_B) {
#pragma unroll
            for (int i = 0; i < 4; ++i) {
                int r = wv * 32 + i * 8 + prRow;
                const short* src = Wb + (bn + r) * (long)K + k0 + prGsrc * 8;
                __builtin_amdgcn_global_load_lds((const AS1 void*)src,
                                                 (AS3 void*)&Bs[(wv * 32 + i * 8) * 64],
                                                 16, 0, 0);
            }
        } else {
#pragma unroll
            for (int i = 0; i < 4; ++i) {
                int r = i * 32 + srow;
                const int4* p = (const int4*)(wq + (bn + r) * (long)K + k0 + scg * 8);
                int4 q0 = p[0], q1 = p[1];
                float s = scales[(bn + r) * (long)(K >> 5) + ((k0 + scg * 8) >> 5)];
                short8 v;
                v[0] = f2bf((float)(q0.x - 128) * s);
                v[1] = f2bf((float)(q0.y - 128) * s);
                v[2] = f2bf((float)(q0.z - 128) * s);
                v[3] = f2bf((float)(q0.w - 128) * s);
                v[4] = f2bf((float)(q1.x - 128) * s);
                v[5] = f2bf((float)(q1.y - 128) * s);
                v[6] = f2bf((float)(q1.z - 128) * s);
                v[7] = f2bf((float)(q1.w - 128) * s);
                int sg = scg ^ (r & 7);
                *(short8*)&Bs[r * 64 + sg * 8] = v;
            }
        }
        __syncthreads();

#pragma unroll
        for (int kk = 0; kk < 2; ++kk) {
            short8 a[4], b[4];
            const int aBase = kk ? aOff1 : aOff0;
            const int bBase = kk ? bOff1 : bOff0;
#pragma unroll
            for (int mi = 0; mi < 4; ++mi) a[mi] = *(const short8*)&As[aBase + mi * 16 * 64];
#pragma unroll
            for (int nj = 0; nj < 4; ++nj) b[nj] = *(const short8*)&Bs[bBase + nj * 16 * 64];
#pragma unroll
            for (int mi = 0; mi < 4; ++mi)
#pragma unroll
                for (int nj = 0; nj < 4; ++nj)
                    acc[mi][nj] = __builtin_amdgcn_mfma_f32_16x16x32_bf16(
                        a[mi], b[nj], acc[mi][nj], 0, 0, 0);
        }
        __syncthreads();
    }

#pragma unroll
    for (int nj = 0; nj < 4; ++nj) {
        long col = bn + wn + nj * 16 + l15;
        float bv = bias[col];
#pragma unroll
        for (int mi = 0; mi < 4; ++mi) {
            long row = bm + wm + mi * 16 + q * 4;
#pragma unroll
            for (int r2 = 0; r2 < 4; ++r2)
                out[(row + r2) * (long)N + col] = acc[mi][nj][r2] + bv;
        }
    }
}

// ---------------- launch ----------------

extern "C" void kernel_launch(void* const* d_in, const int* in_sizes, int n_in,
                              void* d_out, int out_size, void* d_ws, size_t ws_size,
                              hipStream_t stream) {
    const float* x      = (const float*)d_in[0];
    const int*   wq     = (const int*)d_in[1];
    const float* scales = (const float*)d_in[2];
    const float* bias   = (const float*)d_in[3];
    float*       out    = (float*)d_out;

    const long N = (long)in_sizes[3];
    const long K = (long)in_sizes[1] / N;
    const long M = (long)in_sizes[0] / K;

    const size_t needW = (size_t)N * K * sizeof(short);
    const size_t needX = (size_t)M * K * sizeof(short);

    short* Wb = (short*)d_ws;
    short* Xb = Wb + (size_t)N * K;

    const bool preB = (d_ws != nullptr) && ws_size >= needW;
    const bool preA = preB && ws_size >= (needW + needX);

    if (preB) {
        long t8 = N * K / 8;
        prepack_w_kernel<<<dim3((unsigned)((t8 + 255) / 256)), dim3(256), 0, stream>>>(
            wq, scales, Wb, t8);
    }
    if (preA) {
        long t8 = M * K / 8;
        prepack_x_kernel<<<dim3((unsigned)((t8 + 255) / 256)), dim3(256), 0, stream>>>(
            x, Xb, t8);
    }

    const long NTl = K / 64;
    const bool big = preA && (M % 256 == 0) && (N % 256 == 0) && (K % 64 == 0) &&
                     (NTl >= 4) && (NTl % 2 == 0);

    if (big) {
        dim3 grid((unsigned)((M / 256) * (N / 256))), block(512);
        gemm256_kernel<<<grid, block, 0, stream>>>(bias, Xb, Wb, out, (int)M, (int)N, (int)K);
    } else {
        dim3 grid((unsigned)((M / 128) * (N / 128))), block(256);
        if (preA)
            gemm_kernel<true, true><<<grid, block, 0, stream>>>(x, wq, scales, bias, Xb, Wb,
                                                                out, (int)M, (int)N, (int)K);
        else if (preB)
            gemm_kernel<false, true><<<grid, block, 0, stream>>>(x, wq, scales, bias, Xb, Wb,
                                                                 out, (int)M, (int)N, (int)K);
        else
            gemm_kernel<false, false><<<grid, block, 0, stream>>>(x, wq, scales, bias, Xb, Wb,
                                                                  out, (int)M, (int)N, (int)K);
    }
}